// Round 1
// baseline (123.347 us; speedup 1.0000x reference)
//
#include <hip/hip_runtime.h>
#include <math.h>

#define N_ROWS 32768
#define K_CODES 4096
#define DIM 64
#define SPLITS 4
#define TILES_TOTAL (K_CODES / 32)              // 128
#define TILES_PER_SPLIT (TILES_TOTAL / SPLITS)  // 32
#define PHASES (TILES_PER_SPLIT / 2)            // 16 (2 tiles per phase)
#define QUANT_ELEMS (N_ROWS * DIM)              // 2097152

typedef _Float16 half8 __attribute__((ext_vector_type(8)));
typedef float floatx16 __attribute__((ext_vector_type(16)));

// async global->LDS, 16 B per lane (wave-uniform base + lane*16 layout)
__device__ __forceinline__ void gld16(const void* g, void* l) {
    __builtin_amdgcn_global_load_lds(
        (const __attribute__((address_space(1))) unsigned int*)g,
        (__attribute__((address_space(3))) unsigned int*)l, 16, 0, 0);
}

// ---------------------------------------------------------------------------
// Kernel 0 (fused): embed -> fp16 hi/lo B-fragments for mfma_f32_32x32x16_f16
// AND per-code squared norms (LDS reduction).
// Tile c = 32 codes; kstep s covers k=16s..16s+15. Thread t = c*256 + s*64 + l
// holds B[k=(l>>5)*8+j+16s][col=l&31] = embed[c*32+(l&31)][(l>>5)*8+j+16s].
// One 256-thread block per tile (grid = 128 blocks).
// ---------------------------------------------------------------------------
__global__ void prep_kernel(const float* __restrict__ embed,
                            float* __restrict__ sq, half8* __restrict__ ehi,
                            half8* __restrict__ elo) {
    __shared__ float part[256];
    const int tid = threadIdx.x;
    const int t = blockIdx.x * 256 + tid;
    const int l = t & 63;
    const int s = (t >> 6) & 3;
    const int c = blockIdx.x;  // == t >> 8
    const int col = l & 31;
    const int code = c * 32 + col;
    const int koff = (l >> 5) * 8 + 16 * s;
    const float* src = embed + (size_t)code * DIM + koff;
    half8 h, lo;
    float ss = 0.f;
#pragma unroll
    for (int j = 0; j < 8; ++j) {
        float v = src[j];
        ss = fmaf(v, v, ss);
        _Float16 hi = (_Float16)v;
        h[j] = hi;
        lo[j] = (_Float16)(v - (float)hi);
    }
    ehi[t] = h;
    elo[t] = lo;
    part[tid] = ss;
    __syncthreads();
    if (tid < 32) {
        // code (c*32 + tid)'s 8 partials live at tid + 32*h + 64*s
        float a = 0.f;
#pragma unroll
        for (int q = 0; q < 8; ++q) a += part[tid + 32 * (q & 1) + 64 * (q >> 1)];
        sq[c * 32 + tid] = a;
    }
}

// ---------------------------------------------------------------------------
// Kernel 1: fused dist(GEMM 32x32x16) + per-split argmax.
// v2: software-pipelined. Double-buffered 16 KB LDS phases (2 code-tiles per
// phase): stage phase p+1 via global_load_lds BEFORE computing phase p, then
// a single {s_waitcnt vmcnt(0); s_barrier} per phase. Staging latency hides
// under 24 MFMAs; loads stay in flight across compute (no drain-then-compute).
// dist = dot(2x,e) - ||e||^2 ; -||e||^2 = acc init, 2x folded into A (exact).
// fp16 split, 3 terms: xh*eh + xl*eh + xh*el.
// grid = (N_ROWS/128, SPLITS) = (256, 4), block = 256 (4 waves x 32 rows).
// LDS 32 KB/block -> 4 blocks/CU (128 KB of 160 KB), occupancy unchanged.
// ---------------------------------------------------------------------------
#define SUBTILE(LH, LL, NSQ, CIDX)                                            \
    {                                                                         \
        const half8* lh = (const half8*)(LH);                                 \
        const half8* ll = (const half8*)(LL);                                 \
        floatx16 acc;                                                         \
        _Pragma("unroll") for (int r = 0; r < 16; ++r) acc[r] = (NSQ);        \
        half8 b;                                                              \
        __builtin_amdgcn_s_setprio(1);                                        \
        b = lh[lane];                                                         \
        acc = __builtin_amdgcn_mfma_f32_32x32x16_f16(ah[0], b, acc, 0, 0, 0); \
        acc = __builtin_amdgcn_mfma_f32_32x32x16_f16(al[0], b, acc, 0, 0, 0); \
        b = lh[64 + lane];                                                    \
        acc = __builtin_amdgcn_mfma_f32_32x32x16_f16(ah[1], b, acc, 0, 0, 0); \
        acc = __builtin_amdgcn_mfma_f32_32x32x16_f16(al[1], b, acc, 0, 0, 0); \
        b = lh[128 + lane];                                                   \
        acc = __builtin_amdgcn_mfma_f32_32x32x16_f16(ah[2], b, acc, 0, 0, 0); \
        acc = __builtin_amdgcn_mfma_f32_32x32x16_f16(al[2], b, acc, 0, 0, 0); \
        b = lh[192 + lane];                                                   \
        acc = __builtin_amdgcn_mfma_f32_32x32x16_f16(ah[3], b, acc, 0, 0, 0); \
        acc = __builtin_amdgcn_mfma_f32_32x32x16_f16(al[3], b, acc, 0, 0, 0); \
        b = ll[lane];                                                         \
        acc = __builtin_amdgcn_mfma_f32_32x32x16_f16(ah[0], b, acc, 0, 0, 0); \
        b = ll[64 + lane];                                                    \
        acc = __builtin_amdgcn_mfma_f32_32x32x16_f16(ah[1], b, acc, 0, 0, 0); \
        b = ll[128 + lane];                                                   \
        acc = __builtin_amdgcn_mfma_f32_32x32x16_f16(ah[2], b, acc, 0, 0, 0); \
        b = ll[192 + lane];                                                   \
        acc = __builtin_amdgcn_mfma_f32_32x32x16_f16(ah[3], b, acc, 0, 0, 0); \
        __builtin_amdgcn_s_setprio(0);                                        \
        const int cidx = (CIDX);                                              \
        _Pragma("unroll") for (int r = 0; r < 16; ++r) {                      \
            if (acc[r] > best[r]) { /* strict >: earliest tile wins ties */   \
                best[r] = acc[r];                                             \
                bidx[r] = cidx;                                               \
            }                                                                 \
        }                                                                     \
    }

__global__ __launch_bounds__(256, 4) void fused_dist_argmax32(
    const float* __restrict__ x, const float* __restrict__ sq,
    const half8* __restrict__ ehi, const half8* __restrict__ elo,
    float* __restrict__ pbest, int* __restrict__ pidx) {
    // two 16 KB phase buffers; within a buffer:
    // [0,4K)=hi(tile 2p) [4K,8K)=lo(2p) [8K,12K)=hi(2p+1) [12K,16K)=lo(2p+1)
    __shared__ __align__(16) char lbuf[2][16384];
    const int tid = threadIdx.x;
    const int lane = tid & 63;
    const int wave = tid >> 6;
    const int col = lane & 31;    // B col (code within tile); A row
    const int half_ = lane >> 5;  // k-half
    const int row_base = blockIdx.x * 128 + wave * 32;
    const int split = blockIdx.y;
    const int c0 = split * TILES_PER_SPLIT;

    // Persistent A fragments (scaled by 2): A[m=col][k=half_*8+j+16s]
    half8 ah[4], al[4];
    {
        const float* xs = x + (size_t)(row_base + col) * DIM + half_ * 8;
#pragma unroll
        for (int s = 0; s < 4; ++s) {
            half8 h, lo;
#pragma unroll
            for (int j = 0; j < 8; ++j) {
                float v = 2.0f * xs[16 * s + j];
                _Float16 hi = (_Float16)v;
                h[j] = hi;
                lo[j] = (_Float16)(v - (float)hi);
            }
            ah[s] = h;
            al[s] = lo;
        }
    }

    float best[16];
    int bidx[16];
#pragma unroll
    for (int r = 0; r < 16; ++r) {
        best[r] = -INFINITY;
        bidx[r] = 0;
    }

    const char* gh = (const char*)(ehi + (size_t)c0 * 256);
    const char* gl = (const char*)(elo + (size_t)c0 * 256);
    const float* psq = sq + c0 * 32 + col;

    // --- prologue: stage phase 0 (tiles 0,1) into lbuf[0] ---
    {
        char* d = lbuf[0];
        gld16(gh + (size_t)tid * 16, d + tid * 16);
        gld16(gl + (size_t)tid * 16, d + 4096 + tid * 16);
        gld16(gh + 4096 + (size_t)tid * 16, d + 8192 + tid * 16);
        gld16(gl + 4096 + (size_t)tid * 16, d + 12288 + tid * 16);
    }
    float nsqA = -psq[0];
    float nsqB = -psq[32];
    asm volatile("s_waitcnt vmcnt(0)" ::: "memory");
    __builtin_amdgcn_s_barrier();
    asm volatile("" ::: "memory");

    for (int p = 0; p < PHASES; ++p) {
        char* bufc = lbuf[p & 1];
        // prefetch phase p+1 into the other buffer (safe: barrier at end of
        // phase p-1 guarantees all waves finished reading it)
        if (p + 1 < PHASES) {
            char* bufn = lbuf[(p & 1) ^ 1];
            const size_t go = (size_t)(2 * p + 2) * 4096;
            gld16(gh + go + (size_t)tid * 16, bufn + tid * 16);
            gld16(gl + go + (size_t)tid * 16, bufn + 4096 + tid * 16);
            gld16(gh + go + 4096 + (size_t)tid * 16, bufn + 8192 + tid * 16);
            gld16(gl + go + 4096 + (size_t)tid * 16, bufn + 12288 + tid * 16);
        }
        const float nsq0 = nsqA, nsq1 = nsqB;
        if (p + 1 < PHASES) {
            nsqA = -psq[(2 * p + 2) * 32];
            nsqB = -psq[(2 * p + 3) * 32];
        }

        SUBTILE(bufc, bufc + 4096, nsq0, (c0 + 2 * p) * 32 + col);
        SUBTILE(bufc + 8192, bufc + 12288, nsq1, (c0 + 2 * p + 1) * 32 + col);

        // single per-phase sync: drain this phase's prefetch (issued ~24
        // MFMAs ago -> latency hidden), then release buffers to all waves.
        asm volatile("s_waitcnt vmcnt(0)" ::: "memory");
        __builtin_amdgcn_s_barrier();
        asm volatile("" ::: "memory");
    }

    // C/D layout (32x32): col = lane&31, row = (r&3) + 8*(r>>2) + 4*half_.
#pragma unroll
    for (int r = 0; r < 16; ++r) {
        float bv = best[r];
        int bi = bidx[r];
#pragma unroll
        for (int d = 1; d < 32; d <<= 1) {
            float ov = __shfl_xor(bv, d);
            int oi = __shfl_xor(bi, d);
            if (ov > bv || (ov == bv && oi < bi)) {  // smaller idx on tie
                bv = ov;
                bi = oi;
            }
        }
        if (col == 0) {
            const int row = row_base + (r & 3) + 8 * (r >> 2) + 4 * half_;
            pbest[(size_t)split * N_ROWS + row] = bv;
            pidx[(size_t)split * N_ROWS + row] = bi;
        }
    }
}

// ---------------------------------------------------------------------------
// Kernel 2: combine splits, gather quantize rows, write index-as-float.
// One thread per (row, float4-chunk): t in [0, N_ROWS*16).
// ---------------------------------------------------------------------------
__global__ void combine_kernel(const float* __restrict__ pbest,
                               const int* __restrict__ pidx,
                               const float* __restrict__ embed,
                               float* __restrict__ out) {
    const int t = blockIdx.x * blockDim.x + threadIdx.x;
    const int row = t >> 4;
    const int q = t & 15;
    if (row >= N_ROWS) return;

    float best = -INFINITY;
    int bi = 0;
#pragma unroll
    for (int s = 0; s < SPLITS; ++s) {
        float b = pbest[(size_t)s * N_ROWS + row];
        int i = pidx[(size_t)s * N_ROWS + row];
        if (b > best) {  // splits ascending in k; strict > keeps earliest
            best = b;
            bi = i;
        }
    }

    const float4* e4 = reinterpret_cast<const float4*>(embed);
    float4 v = e4[(size_t)bi * (DIM / 4) + q];
    reinterpret_cast<float4*>(out)[(size_t)row * (DIM / 4) + q] = v;
    if (q == 0) {
        out[(size_t)QUANT_ELEMS + row] = (float)bi;  // index as float
    }
}

// ---------------------------------------------------------------------------
extern "C" void kernel_launch(void* const* d_in, const int* in_sizes, int n_in,
                              void* d_out, int out_size, void* d_ws,
                              size_t ws_size, hipStream_t stream) {
    const float* x = (const float*)d_in[0];
    const float* embed = (const float*)d_in[1];
    float* out = (float*)d_out;

    // ws: sq 16KB | ehi 512KB | elo 512KB | pbest 512KB | pidx 512KB
    char* ws = (char*)d_ws;
    float* sq = (float*)ws;
    half8* ehi = (half8*)(ws + 16384);
    half8* elo = (half8*)(ws + 16384 + 524288);
    float* pbest = (float*)(ws + 16384 + 2 * 524288);
    int* pidx = (int*)(ws + 16384 + 2 * 524288 + SPLITS * N_ROWS * 4);

    prep_kernel<<<TILES_TOTAL, 256, 0, stream>>>(embed, sq, ehi, elo);

    dim3 grid(N_ROWS / 128, SPLITS);
    fused_dist_argmax32<<<grid, 256, 0, stream>>>(x, sq, ehi, elo, pbest,
                                                  pidx);

    const int combine_threads = N_ROWS * (DIM / 4);
    combine_kernel<<<(combine_threads + 255) / 256, 256, 0, stream>>>(
        pbest, pidx, embed, out);
}